// Round 13
// baseline (706.944 us; speedup 1.0000x reference)
//
#include <hip/hip_runtime.h>

// ---------------------------------------------------------------------------
// MatchNetAssign: 65536x128 pairs -> MLP(6->64->32->1) -> sigmoid -> clamp<0.5
// -> per-target top-8 -> reorder by argsort(-targets[:,1], stable).
// ROUND 18: round-17 post-mortem: laundering DEFEATED (VGPR stayed 40, K1
// 157.6->163.7 — allocator spilled around the asm). New discovery: k3_refine
// = 226us top dispatch at 0.26% occupancy/VALUBusy -> straggler-tail
// (1 block/target, m~CAP=4096 on heavy targets, half the CUs idle).
// CHANGES:
//  K1: 64 pairs/wave-iter — each lane loads ITS OWN pair (kills 4x redundant
//      input loads), packs 3 feat words; group c's bfeat = shfl from lane
//      c*16+lo4 (12 shfl/big-iter); per-group L1/L2/L3 byte-identical to the
//      verified path; weight setup amortizes 4x; 4x fewer iterations.
//      Laundering removed (regressed).
//  K3: 8 blocks/target (grid 1024), slice i=b+8k, per-slice top-8 (same
//      comparator), partials into the DEAD lg region (no new workspace);
//      K4 merges 64 entries/target (order-independent selection, n unique).
// Predict: K1 -> 50-120us, K3 top <70us + occupancy >2%, total ~460-560us.
// K2a/K2b/K2c frozen.
// ---------------------------------------------------------------------------

typedef unsigned int   u32;
typedef unsigned short u16;
typedef short s8v  __attribute__((ext_vector_type(8)));   // 8 bf16 = 4 VGPR
typedef float f4v  __attribute__((ext_vector_type(4)));   // 16x16 accum

#define N_PROP   65536
#define N_TGT    128
#define N_PAIR   (N_PROP * N_TGT)      // 8388608
#define CAP      4096
#define MARGIN   0.15f
#define NCHUNK   512                   // K2a/K2c row-chunks (128 rows each)
#define K3SPLIT  8
#define SLICE_CAP (CAP / K3SPLIT)      // 512

static __device__ __forceinline__ u32 packbf(float a, float b) {
  // low16 = bf16_trunc(a), high16 = bf16_trunc(b)  (single v_perm_b32)
  return __builtin_amdgcn_perm(__float_as_uint(b), __float_as_uint(a), 0x07060302u);
}
static __device__ __forceinline__ float bf16_rne(float x) {
  u32 u = __float_as_uint(x);
  u = u + 0x7fffu + ((u >> 16) & 1u);
  return __uint_as_float(u & 0xffff0000u);
}
static __device__ __forceinline__ float bf2f(u16 u) {
  return __uint_as_float(((u32)u) << 16);
}
static __device__ __forceinline__ s8v mk_frag(u32 a, u32 b, u32 c, u32 d) {
  union { u32 u[4]; s8v v; } x;
  x.u[0] = a; x.u[1] = b; x.u[2] = c; x.u[3] = d;
  return x.v;
}
static __device__ __forceinline__ f4v MF16(s8v a, s8v b, f4v c) {
  return __builtin_amdgcn_mfma_f32_16x16x32_bf16(a, b, c, 0, 0, 0);
}

// ---------------------------------------------------------------------------
// K1: 64 pairs per wave-iteration (4 groups of 16), all three layers on wave.
//  Lane loads pair base=g*64+l (coalesced, no redundancy), packs pw0..pw2.
//  Group c: bfeat words broadcast from lane c*16+lo4 (q0 slots only, bias
//  1.0 at k=6). L1: h1-tile mt = MF(aw1[mt], bfeat); relu+pack -> hl/hh.
//  L2 (bridge-free): W2 rows permuted u=16*(2c+(j>>2))+4q+(j&3);
//  b2f=(hl,hh) pairs. L3: per-lane dot + quad butterfly; q0 stores logit at
//  g*64+c*16+lo4. All per-group math identical to the round-15-verified path.
// ---------------------------------------------------------------------------
__global__ __launch_bounds__(256, 4) void k1_mfma(
    const float* __restrict__ p_th, const float* __restrict__ p_xy,
    const float* __restrict__ p_di, const float* __restrict__ p_po,
    const float* __restrict__ p_ne, const float* __restrict__ p_io,
    const float* __restrict__ W1, const float* __restrict__ b1,
    const float* __restrict__ W2, const float* __restrict__ b2,
    const float* __restrict__ W3, const float* __restrict__ b3,
    u16* __restrict__ lgout)
{
  const int tid = threadIdx.x;
  const int l   = tid & 63;
  const int lo4 = l & 15;
  const int q   = (l >> 4) & 3;

  // ---- A-frags for L1: W1^T m-tiles (k = 8q+j; nonzero only for q==0) ----
  s8v aw1[4];
#pragma unroll
  for (int mt = 0; mt < 4; ++mt) {
    float v[8];
#pragma unroll
    for (int j = 0; j < 8; ++j) {
      const int k = 8 * q + j;
      float x = 0.0f;
      if (k < 6)       x = W1[k * 64 + 16 * mt + lo4];
      else if (k == 6) x = b1[16 * mt + lo4];
      v[j] = bf16_rne(x);
    }
    aw1[mt] = mk_frag(packbf(v[0], v[1]), packbf(v[2], v[3]),
                      packbf(v[4], v[5]), packbf(v[6], v[7]));
  }

  // ---- A-frags for L2: W2^T with PERMUTED rows (bridge-free k order) ----
  // k-slot (c, 8q+j) sums h1 unit u = 16*(2c + (j>>2)) + 4q + (j&3).
  s8v aw2[2][2];
#pragma unroll
  for (int mt = 0; mt < 2; ++mt)
#pragma unroll
    for (int c = 0; c < 2; ++c) {
      float v[8];
#pragma unroll
      for (int j = 0; j < 8; ++j) {
        const int u = 16 * (2 * c + (j >> 2)) + 4 * q + (j & 3);
        v[j] = bf16_rne(W2[u * 32 + 16 * mt + lo4]);
      }
      aw2[mt][c] = mk_frag(packbf(v[0], v[1]), packbf(v[2], v[3]),
                           packbf(v[4], v[5]), packbf(v[6], v[7]));
    }

  // ---- per-lane b2/W3 rows from C/D mapping (round-4-verified) ----
  float b2l[2][4], w3l[2][4];
#pragma unroll
  for (int mt = 0; mt < 2; ++mt)
#pragma unroll
    for (int r = 0; r < 4; ++r) {
      const int row = 16 * mt + 4 * q + r;
      b2l[mt][r] = b2[row];
      w3l[mt][r] = W3[row];
    }
  const float b3s = b3[0];
  const f4v Z4 = {};
  const bool q0 = (q == 0);

  const int nwaves = (gridDim.x * blockDim.x) >> 6;      // 8192
  const int w0i = (blockIdx.x * blockDim.x + tid) >> 6;
  const int NG64 = N_PAIR / 64;                          // 131072

  for (int g = w0i; g < NG64; g += nwaves) {
    const int base = g * 64 + l;                         // lane's own pair
    const float x0 = p_th[base], x1 = p_xy[base], x2 = p_di[base];
    const float x3 = p_po[base], x4 = p_ne[base], x5 = p_io[base];
    const float f0 = fmaf(fminf(x0, 180.0f), -(1.0f / 180.0f), 1.0f);
    const float f1 = fmaf(fminf(x1, 800.0f), -(1.0f / 800.0f), 1.0f);
    const float f2 = fmaf(fminf(x2, 800.0f), -(1.0f / 800.0f), 1.0f);
    const u32 pw0 = packbf(f0, f1);
    const u32 pw1 = packbf(f2, x3);
    const u32 pw2 = packbf(x4, x5);

#pragma unroll
    for (int c = 0; c < 4; ++c) {
      const int s = c * 16 + lo4;                        // src lane of group c
      const u32 a0 = (u32)__shfl((int)pw0, s, 64);
      const u32 a1 = (u32)__shfl((int)pw1, s, 64);
      const u32 a2 = (u32)__shfl((int)pw2, s, 64);
      const s8v bfeat = mk_frag(q0 ? a0 : 0u, q0 ? a1 : 0u,
                                q0 ? a2 : 0u, q0 ? 0x00003f80u : 0u);

      // ---- L1: 4 m-tiles of h1 ----
      u32 hl[4], hh[4];
#pragma unroll
      for (int mt = 0; mt < 4; ++mt) {
        const f4v hv = MF16(aw1[mt], bfeat, Z4);
        hl[mt] = packbf(fmaxf(hv[0], 0.0f), fmaxf(hv[1], 0.0f));
        hh[mt] = packbf(fmaxf(hv[2], 0.0f), fmaxf(hv[3], 0.0f));
      }

      // ---- B-frags for L2: C/D-native regs ----
      const s8v b2f0 = mk_frag(hl[0], hh[0], hl[1], hh[1]);
      const s8v b2f1 = mk_frag(hl[2], hh[2], hl[3], hh[3]);

      // ---- L2 ----
      f4v acc0 = Z4, acc1 = Z4;
      acc0 = MF16(aw2[0][0], b2f0, acc0);
      acc0 = MF16(aw2[0][1], b2f1, acc0);
      acc1 = MF16(aw2[1][0], b2f0, acc1);
      acc1 = MF16(aw2[1][1], b2f1, acc1);

      // ---- L3 ----
      float part = 0.0f;
#pragma unroll
      for (int r = 0; r < 4; ++r) {
        part = fmaf(w3l[0][r], fmaxf(acc0[r] + b2l[0][r], 0.0f), part);
        part = fmaf(w3l[1][r], fmaxf(acc1[r] + b2l[1][r], 0.0f), part);
      }
      part += __shfl_xor(part, 16, 64);
      part += __shfl_xor(part, 32, 64);

      if (q0)
        lgout[g * 64 + c * 16 + lo4] = (u16)(__float_as_uint(part + b3s) >> 16);
    }
  }
}

// ---------------------------------------------------------------------------
// K2a: per-(chunk, target) top-8 approx values. NCHUNK blocks x 128 threads.
// ---------------------------------------------------------------------------
__global__ void k2a_part(const u16* __restrict__ lg, float* __restrict__ pval)
{
  const int t = threadIdx.x;       // 0..127
  const int c = blockIdx.x;        // 0..NCHUNK-1
  const size_t base = (size_t)c * 128 * 128 + t;
  float v[8];
#pragma unroll
  for (int q = 0; q < 8; ++q) v[q] = -3.4e38f;
#pragma unroll 4
  for (int i = 0; i < 128; ++i) {
    const float x = bf2f(lg[base + (size_t)i * 128]);
    if (x > v[7]) {
      int k = 7;
      while (k > 0 && x > v[k - 1]) { v[k] = v[k - 1]; --k; }
      v[k] = x;
    }
  }
  float* o = pval + ((size_t)c * 128 + t) * 8;
#pragma unroll
  for (int q = 0; q < 8; ++q) o[q] = v[q];
}

// K2b: merge NCHUNK partials per target -> tau[t] = (8th approx) - MARGIN.
__global__ void k2b_merge(const float* __restrict__ pval, float* __restrict__ tau)
{
  __shared__ float sm[64 * 8];
  const int t = blockIdx.x;
  const int i = threadIdx.x;       // 0..63
  float v[8];
#pragma unroll
  for (int q = 0; q < 8; ++q) v[q] = -3.4e38f;
  for (int e = i; e < NCHUNK * 8; e += 64) {
    const float x = pval[(size_t)(e >> 3) * 1024 + (size_t)t * 8 + (e & 7)];
    if (x > v[7]) {
      int k = 7;
      while (k > 0 && x > v[k - 1]) { v[k] = v[k - 1]; --k; }
      v[k] = x;
    }
  }
#pragma unroll
  for (int q = 0; q < 8; ++q) sm[i * 8 + q] = v[q];
  __syncthreads();
  if (i == 0) {
    float w[8];
#pragma unroll
    for (int q = 0; q < 8; ++q) w[q] = -3.4e38f;
    for (int e = 0; e < 512; ++e) {
      const float x = sm[e];
      if (x > w[7]) {
        int k = 7;
        while (k > 0 && x > w[k - 1]) { w[k] = w[k - 1]; --k; }
        w[k] = x;
      }
    }
    tau[t] = w[7] - MARGIN;
  }
}

// K2c: collect candidates: approx >= tau, plus forced n<16 (zero-fill ties).
__global__ void k2c_cand(const u16* __restrict__ lg, const float* __restrict__ tau,
                         int* __restrict__ cnt, int* __restrict__ cand)
{
  const int t = threadIdx.x;
  const int c = blockIdx.x;
  const int n0 = c * 128;
  const float ta = tau[t];
#pragma unroll 4
  for (int i = 0; i < 128; ++i) {
    const int n = n0 + i;
    const float x = bf2f(lg[(size_t)n * 128 + t]);
    if (x >= ta || n < 16) {
      const int p = atomicAdd(&cnt[t], 1);
      if (p < CAP) cand[(size_t)t * CAP + p] = n;
    }
  }
}

// ---------------------------------------------------------------------------
// K3: exact f32 refine, 8 blocks per target (slice b handles i = b + 8k).
// Per-slice top-8 with exact ref comparator (key desc, idx asc) -> partials.
// ---------------------------------------------------------------------------
__global__ __launch_bounds__(256) void k3_refine(
    const float* __restrict__ p_th, const float* __restrict__ p_xy,
    const float* __restrict__ p_di, const float* __restrict__ p_po,
    const float* __restrict__ p_ne, const float* __restrict__ p_io,
    const float* __restrict__ W1, const float* __restrict__ b1,
    const float* __restrict__ W2, const float* __restrict__ b2,
    const float* __restrict__ W3, const float* __restrict__ b3,
    const int* __restrict__ cnt, const int* __restrict__ cand,
    int* __restrict__ t8i_p, float* __restrict__ t8k_p)
{
  __shared__ float wl[2561];
  __shared__ float ck[SLICE_CAP];
  __shared__ int   cnid[SLICE_CAP];
  const int t   = blockIdx.x >> 3;          // target
  const int b   = blockIdx.x & (K3SPLIT - 1);
  const int tid = threadIdx.x;

  for (int i = tid; i < 2561; i += 256) {
    float x;
    if (i < 384)       x = W1[i];
    else if (i < 448)  x = b1[i - 384];
    else if (i < 2496) x = W2[i - 448];
    else if (i < 2528) x = b2[i - 2496];
    else if (i < 2560) x = W3[i - 2528];
    else               x = b3[0];
    wl[i] = x;
  }
  __syncthreads();
  const float* W1L = wl;
  const float* b1L = wl + 384;
  const float* W2L = wl + 448;
  const float* b2L = wl + 2496;
  const float* W3L = wl + 2528;
  const float  b3s = wl[2560];

  int m = cnt[t];
  if (m > CAP) m = CAP;
  const int mloc = (b < m) ? (m - b + K3SPLIT - 1) / K3SPLIT : 0;

  for (int k = tid; k < mloc; k += 256) {
    const int i = b + k * K3SPLIT;          // global candidate index, < m
    const int n = cand[(size_t)t * CAP + i];
    const size_t off = (size_t)n * 128 + t;
    float f[6];
    f[0] = 1.0f - fminf(p_th[off], 180.0f) / 180.0f;
    f[1] = 1.0f - fminf(p_xy[off], 800.0f) / 800.0f;
    f[2] = 1.0f - fminf(p_di[off], 800.0f) / 800.0f;
    f[3] = p_po[off]; f[4] = p_ne[off]; f[5] = p_io[off];

    float h1[64];
#pragma unroll
    for (int j = 0; j < 64; ++j) {
      float s = b1L[j];
#pragma unroll
      for (int k2 = 0; k2 < 6; ++k2) s = fmaf(f[k2], W1L[k2 * 64 + j], s);
      h1[j] = fmaxf(s, 0.0f);
    }
    float h2[32];
#pragma unroll
    for (int j = 0; j < 32; ++j) {
      float s = b2L[j];
#pragma unroll
      for (int k2 = 0; k2 < 64; ++k2) s = fmaf(h1[k2], W2L[k2 * 32 + j], s);
      h2[j] = fmaxf(s, 0.0f);
    }
    float lo = b3s;
#pragma unroll
    for (int k2 = 0; k2 < 32; ++k2) lo = fmaf(h2[k2], W3L[k2], lo);
    const float sg = 1.0f / (1.0f + expf(-lo));
    ck[k]   = (sg < 0.5f) ? 0.0f : sg;
    cnid[k] = n;
  }
  __syncthreads();

  if (tid == 0) {
    float bv[8]; int bi[8];
#pragma unroll
    for (int q = 0; q < 8; ++q) { bv[q] = -1.0f; bi[q] = 0x7fffffff; }
    for (int i = 0; i < mloc; ++i) {
      const float x = ck[i];
      const int   n = cnid[i];
      if (x > bv[7] || (x == bv[7] && n < bi[7])) {
        int k = 7;
        while (k > 0 && (x > bv[k - 1] || (x == bv[k - 1] && n < bi[k - 1]))) {
          bv[k] = bv[k - 1]; bi[k] = bi[k - 1]; --k;
        }
        bv[k] = x; bi[k] = n;
      }
    }
    const int o = (t * K3SPLIT + b) * 8;
#pragma unroll
    for (int q = 0; q < 8; ++q) {
      t8i_p[o + q] = bi[q];
      t8k_p[o + q] = bv[q];
    }
  }
}

// ---------------------------------------------------------------------------
// K4: stable descending argsort of targets[:,1]; merge the 8x8 partials per
// target (same comparator -> identical selection); assemble outputs.
// d_out (int32): rows[1024] | cols[1024] | valid[1024]
// ---------------------------------------------------------------------------
__global__ void k4_final(const float* __restrict__ targets,
                         const int* __restrict__ t8i_p,
                         const float* __restrict__ t8k_p,
                         int* __restrict__ out)
{
  __shared__ float key[128];
  __shared__ int   ord[128];
  const int i = threadIdx.x;    // 0..127
  key[i] = targets[i * 4 + 1];
  __syncthreads();
  const float ki = key[i];
  int r = 0;
  for (int j = 0; j < 128; ++j) {
    const float kj = key[j];
    r += (kj > ki) || (kj == ki && j < i);
  }
  ord[r] = i;
  __syncthreads();
  const int src = ord[i];

  float bv[8]; int bi[8];
#pragma unroll
  for (int q = 0; q < 8; ++q) { bv[q] = -1.0f; bi[q] = 0x7fffffff; }
  for (int e = 0; e < K3SPLIT * 8; ++e) {
    const float x = t8k_p[src * K3SPLIT * 8 + e];
    const int   n = t8i_p[src * K3SPLIT * 8 + e];
    if (x > bv[7] || (x == bv[7] && n < bi[7])) {
      int k = 7;
      while (k > 0 && (x > bv[k - 1] || (x == bv[k - 1] && n < bi[k - 1]))) {
        bv[k] = bv[k - 1]; bi[k] = bi[k - 1]; --k;
      }
      bv[k] = x; bi[k] = n;
    }
  }
#pragma unroll
  for (int k = 0; k < 8; ++k) {
    out[i * 8 + k]        = bi[k];
    out[1024 + i * 8 + k] = src;
    out[2048 + i * 8 + k] = (bv[k] > 0.0f) ? 1 : 0;
  }
}

// ---------------------------------------------------------------------------
extern "C" void kernel_launch(void* const* d_in, const int* in_sizes, int n_in,
                              void* d_out, int out_size, void* d_ws, size_t ws_size,
                              hipStream_t stream)
{
  const float* p_th = (const float*)d_in[0];
  const float* p_xy = (const float*)d_in[1];
  const float* p_di = (const float*)d_in[2];
  const float* p_po = (const float*)d_in[3];
  const float* p_ne = (const float*)d_in[4];
  const float* p_io = (const float*)d_in[5];
  const float* tgt  = (const float*)d_in[6];
  const float* W1   = (const float*)d_in[7];
  const float* b1   = (const float*)d_in[8];
  const float* W2   = (const float*)d_in[9];
  const float* b2   = (const float*)d_in[10];
  const float* W3   = (const float*)d_in[11];
  const float* b3   = (const float*)d_in[12];

  // workspace carve (~18.9 MB; pval and cand share a 2 MB region, disjoint
  // lifetimes: pval dead after k2b, cand born in k2c). K3/K4 partials live
  // in the lg region (lg dead after k2c reads it).
  char* base = (char*)d_ws;
  u16*   lg    = (u16*)  (base);                 // 16,777,216 B (k1..k2c)
  int*   t8i_p = (int*)  (base);                 //     32,768 B (k3..k4)
  float* t8k_p = (float*)(base + 32768);         //     32,768 B (k3..k4)
  float* pval  = (float*)(base + 16777216);      //  2,097,152 B (k2a..k2b)
  int*   cand  = (int*)  (base + 16777216);      //  2,097,152 B (k2c..k3)
  float* tau   = (float*)(base + 18874368);      //        512 B
  int*   cnt   = (int*)  (base + 18874880);      //        512 B

  hipMemsetAsync(cnt, 0, 128 * sizeof(int), stream);

  k1_mfma<<<2048, 256, 0, stream>>>(p_th, p_xy, p_di, p_po, p_ne, p_io,
                                    W1, b1, W2, b2, W3, b3, lg);
  k2a_part<<<NCHUNK, 128, 0, stream>>>(lg, pval);
  k2b_merge<<<128, 64, 0, stream>>>(pval, tau);
  k2c_cand<<<NCHUNK, 128, 0, stream>>>(lg, tau, cnt, cand);
  k3_refine<<<N_TGT * K3SPLIT, 256, 0, stream>>>(p_th, p_xy, p_di, p_po, p_ne,
                                                 p_io, W1, b1, W2, b2, W3, b3,
                                                 cnt, cand, t8i_p, t8k_p);
  k4_final<<<1, 128, 0, stream>>>(tgt, t8i_p, t8k_p, (int*)d_out);
}

// Round 19
// 581.960 us; speedup vs baseline: 1.2148x; 1.2148x over previous
//
#include <hip/hip_runtime.h>

// ---------------------------------------------------------------------------
// MatchNetAssign: 65536x128 pairs -> MLP(6->64->32->1) -> sigmoid -> clamp<0.5
// -> per-target top-8 -> reorder by argsort(-targets[:,1], stable).
// ROUND 24: resubmit (timeouts #10-#14; chunked-K3 never run). Held over a
// considered K1-revert bundle: both K1 variants are verified, EVs within
// noise, and holding preserves the K1-64pair A/B measurement. Theory:
// r18 counters showed K3 at VGPR=256 (allocator max) -> h1/h2 spill to
// scratch; r12 re-analysis shows the 226us K3 was cold-start _ord 0 and the
// 8x split REGRESSED steady K3 (~160->198) -> spills dominate both variants.
// FIX: chunked K3 MLP — h1 in 4 chunks of 16 (rolled c0 loop), h2
// accumulated in the SAME ascending k2 order (bitwise-identical; relu folded
// into W3 dot), live ~60 regs, __launch_bounds__(256,4). Edge cases checked:
// m=4096 -> mloc=512=SLICE_CAP exactly; empty slices emit sentinels K4
// ranks last. Decisive: K3 VGPR 256->~128. Predict K3 198->25-60us, K1 true
// dur surfaces (150-190 decides revert-vs-keep), total 707->~500-570us.
// K1 (64-pair, verified r18) / K2* / K4 (merge, verified r18) frozen.
// ---------------------------------------------------------------------------

typedef unsigned int   u32;
typedef unsigned short u16;
typedef short s8v  __attribute__((ext_vector_type(8)));   // 8 bf16 = 4 VGPR
typedef float f4v  __attribute__((ext_vector_type(4)));   // 16x16 accum

#define N_PROP   65536
#define N_TGT    128
#define N_PAIR   (N_PROP * N_TGT)      // 8388608
#define CAP      4096
#define MARGIN   0.15f
#define NCHUNK   512                   // K2a/K2c row-chunks (128 rows each)
#define K3SPLIT  8
#define SLICE_CAP (CAP / K3SPLIT)      // 512

static __device__ __forceinline__ u32 packbf(float a, float b) {
  // low16 = bf16_trunc(a), high16 = bf16_trunc(b)  (single v_perm_b32)
  return __builtin_amdgcn_perm(__float_as_uint(b), __float_as_uint(a), 0x07060302u);
}
static __device__ __forceinline__ float bf16_rne(float x) {
  u32 u = __float_as_uint(x);
  u = u + 0x7fffu + ((u >> 16) & 1u);
  return __uint_as_float(u & 0xffff0000u);
}
static __device__ __forceinline__ float bf2f(u16 u) {
  return __uint_as_float(((u32)u) << 16);
}
static __device__ __forceinline__ s8v mk_frag(u32 a, u32 b, u32 c, u32 d) {
  union { u32 u[4]; s8v v; } x;
  x.u[0] = a; x.u[1] = b; x.u[2] = c; x.u[3] = d;
  return x.v;
}
static __device__ __forceinline__ f4v MF16(s8v a, s8v b, f4v c) {
  return __builtin_amdgcn_mfma_f32_16x16x32_bf16(a, b, c, 0, 0, 0);
}

// ---------------------------------------------------------------------------
// K1: 64 pairs per wave-iteration (4 groups of 16), all three layers on wave.
//  Lane loads pair base=g*64+l (coalesced, no redundancy), packs pw0..pw2.
//  Group c: bfeat words broadcast from lane c*16+lo4 (q0 slots only, bias
//  1.0 at k=6). L1: h1-tile mt = MF(aw1[mt], bfeat); relu+pack -> hl/hh.
//  L2 (bridge-free): W2 rows permuted u=16*(2c+(j>>2))+4q+(j&3);
//  b2f=(hl,hh) pairs. L3: per-lane dot + quad butterfly; q0 stores logit at
//  g*64+c*16+lo4. All per-group math identical to the round-15-verified path.
// ---------------------------------------------------------------------------
__global__ __launch_bounds__(256, 4) void k1_mfma(
    const float* __restrict__ p_th, const float* __restrict__ p_xy,
    const float* __restrict__ p_di, const float* __restrict__ p_po,
    const float* __restrict__ p_ne, const float* __restrict__ p_io,
    const float* __restrict__ W1, const float* __restrict__ b1,
    const float* __restrict__ W2, const float* __restrict__ b2,
    const float* __restrict__ W3, const float* __restrict__ b3,
    u16* __restrict__ lgout)
{
  const int tid = threadIdx.x;
  const int l   = tid & 63;
  const int lo4 = l & 15;
  const int q   = (l >> 4) & 3;

  // ---- A-frags for L1: W1^T m-tiles (k = 8q+j; nonzero only for q==0) ----
  s8v aw1[4];
#pragma unroll
  for (int mt = 0; mt < 4; ++mt) {
    float v[8];
#pragma unroll
    for (int j = 0; j < 8; ++j) {
      const int k = 8 * q + j;
      float x = 0.0f;
      if (k < 6)       x = W1[k * 64 + 16 * mt + lo4];
      else if (k == 6) x = b1[16 * mt + lo4];
      v[j] = bf16_rne(x);
    }
    aw1[mt] = mk_frag(packbf(v[0], v[1]), packbf(v[2], v[3]),
                      packbf(v[4], v[5]), packbf(v[6], v[7]));
  }

  // ---- A-frags for L2: W2^T with PERMUTED rows (bridge-free k order) ----
  // k-slot (c, 8q+j) sums h1 unit u = 16*(2c + (j>>2)) + 4q + (j&3).
  s8v aw2[2][2];
#pragma unroll
  for (int mt = 0; mt < 2; ++mt)
#pragma unroll
    for (int c = 0; c < 2; ++c) {
      float v[8];
#pragma unroll
      for (int j = 0; j < 8; ++j) {
        const int u = 16 * (2 * c + (j >> 2)) + 4 * q + (j & 3);
        v[j] = bf16_rne(W2[u * 32 + 16 * mt + lo4]);
      }
      aw2[mt][c] = mk_frag(packbf(v[0], v[1]), packbf(v[2], v[3]),
                           packbf(v[4], v[5]), packbf(v[6], v[7]));
    }

  // ---- per-lane b2/W3 rows from C/D mapping (round-4-verified) ----
  float b2l[2][4], w3l[2][4];
#pragma unroll
  for (int mt = 0; mt < 2; ++mt)
#pragma unroll
    for (int r = 0; r < 4; ++r) {
      const int row = 16 * mt + 4 * q + r;
      b2l[mt][r] = b2[row];
      w3l[mt][r] = W3[row];
    }
  const float b3s = b3[0];
  const f4v Z4 = {};
  const bool q0 = (q == 0);

  const int nwaves = (gridDim.x * blockDim.x) >> 6;      // 8192
  const int w0i = (blockIdx.x * blockDim.x + tid) >> 6;
  const int NG64 = N_PAIR / 64;                          // 131072

  for (int g = w0i; g < NG64; g += nwaves) {
    const int base = g * 64 + l;                         // lane's own pair
    const float x0 = p_th[base], x1 = p_xy[base], x2 = p_di[base];
    const float x3 = p_po[base], x4 = p_ne[base], x5 = p_io[base];
    const float f0 = fmaf(fminf(x0, 180.0f), -(1.0f / 180.0f), 1.0f);
    const float f1 = fmaf(fminf(x1, 800.0f), -(1.0f / 800.0f), 1.0f);
    const float f2 = fmaf(fminf(x2, 800.0f), -(1.0f / 800.0f), 1.0f);
    const u32 pw0 = packbf(f0, f1);
    const u32 pw1 = packbf(f2, x3);
    const u32 pw2 = packbf(x4, x5);

#pragma unroll
    for (int c = 0; c < 4; ++c) {
      const int s = c * 16 + lo4;                        // src lane of group c
      const u32 a0 = (u32)__shfl((int)pw0, s, 64);
      const u32 a1 = (u32)__shfl((int)pw1, s, 64);
      const u32 a2 = (u32)__shfl((int)pw2, s, 64);
      const s8v bfeat = mk_frag(q0 ? a0 : 0u, q0 ? a1 : 0u,
                                q0 ? a2 : 0u, q0 ? 0x00003f80u : 0u);

      // ---- L1: 4 m-tiles of h1 ----
      u32 hl[4], hh[4];
#pragma unroll
      for (int mt = 0; mt < 4; ++mt) {
        const f4v hv = MF16(aw1[mt], bfeat, Z4);
        hl[mt] = packbf(fmaxf(hv[0], 0.0f), fmaxf(hv[1], 0.0f));
        hh[mt] = packbf(fmaxf(hv[2], 0.0f), fmaxf(hv[3], 0.0f));
      }

      // ---- B-frags for L2: C/D-native regs ----
      const s8v b2f0 = mk_frag(hl[0], hh[0], hl[1], hh[1]);
      const s8v b2f1 = mk_frag(hl[2], hh[2], hl[3], hh[3]);

      // ---- L2 ----
      f4v acc0 = Z4, acc1 = Z4;
      acc0 = MF16(aw2[0][0], b2f0, acc0);
      acc0 = MF16(aw2[0][1], b2f1, acc0);
      acc1 = MF16(aw2[1][0], b2f0, acc1);
      acc1 = MF16(aw2[1][1], b2f1, acc1);

      // ---- L3 ----
      float part = 0.0f;
#pragma unroll
      for (int r = 0; r < 4; ++r) {
        part = fmaf(w3l[0][r], fmaxf(acc0[r] + b2l[0][r], 0.0f), part);
        part = fmaf(w3l[1][r], fmaxf(acc1[r] + b2l[1][r], 0.0f), part);
      }
      part += __shfl_xor(part, 16, 64);
      part += __shfl_xor(part, 32, 64);

      if (q0)
        lgout[g * 64 + c * 16 + lo4] = (u16)(__float_as_uint(part + b3s) >> 16);
    }
  }
}

// ---------------------------------------------------------------------------
// K2a: per-(chunk, target) top-8 approx values. NCHUNK blocks x 128 threads.
// ---------------------------------------------------------------------------
__global__ void k2a_part(const u16* __restrict__ lg, float* __restrict__ pval)
{
  const int t = threadIdx.x;       // 0..127
  const int c = blockIdx.x;        // 0..NCHUNK-1
  const size_t base = (size_t)c * 128 * 128 + t;
  float v[8];
#pragma unroll
  for (int q = 0; q < 8; ++q) v[q] = -3.4e38f;
#pragma unroll 4
  for (int i = 0; i < 128; ++i) {
    const float x = bf2f(lg[base + (size_t)i * 128]);
    if (x > v[7]) {
      int k = 7;
      while (k > 0 && x > v[k - 1]) { v[k] = v[k - 1]; --k; }
      v[k] = x;
    }
  }
  float* o = pval + ((size_t)c * 128 + t) * 8;
#pragma unroll
  for (int q = 0; q < 8; ++q) o[q] = v[q];
}

// K2b: merge NCHUNK partials per target -> tau[t] = (8th approx) - MARGIN.
__global__ void k2b_merge(const float* __restrict__ pval, float* __restrict__ tau)
{
  __shared__ float sm[64 * 8];
  const int t = blockIdx.x;
  const int i = threadIdx.x;       // 0..63
  float v[8];
#pragma unroll
  for (int q = 0; q < 8; ++q) v[q] = -3.4e38f;
  for (int e = i; e < NCHUNK * 8; e += 64) {
    const float x = pval[(size_t)(e >> 3) * 1024 + (size_t)t * 8 + (e & 7)];
    if (x > v[7]) {
      int k = 7;
      while (k > 0 && x > v[k - 1]) { v[k] = v[k - 1]; --k; }
      v[k] = x;
    }
  }
#pragma unroll
  for (int q = 0; q < 8; ++q) sm[i * 8 + q] = v[q];
  __syncthreads();
  if (i == 0) {
    float w[8];
#pragma unroll
    for (int q = 0; q < 8; ++q) w[q] = -3.4e38f;
    for (int e = 0; e < 512; ++e) {
      const float x = sm[e];
      if (x > w[7]) {
        int k = 7;
        while (k > 0 && x > w[k - 1]) { w[k] = w[k - 1]; --k; }
        w[k] = x;
      }
    }
    tau[t] = w[7] - MARGIN;
  }
}

// K2c: collect candidates: approx >= tau, plus forced n<16 (zero-fill ties).
__global__ void k2c_cand(const u16* __restrict__ lg, const float* __restrict__ tau,
                         int* __restrict__ cnt, int* __restrict__ cand)
{
  const int t = threadIdx.x;
  const int c = blockIdx.x;
  const int n0 = c * 128;
  const float ta = tau[t];
#pragma unroll 4
  for (int i = 0; i < 128; ++i) {
    const int n = n0 + i;
    const float x = bf2f(lg[(size_t)n * 128 + t]);
    if (x >= ta || n < 16) {
      const int p = atomicAdd(&cnt[t], 1);
      if (p < CAP) cand[(size_t)t * CAP + p] = n;
    }
  }
}

// ---------------------------------------------------------------------------
// K3: exact f32 refine, 8 blocks per target (slice b handles i = b + 8k).
// CHUNKED MLP: h1 in 4 chunks of 16 (rolled c0 loop, reused regs); h2[j]
// accumulated b2-first then k2 ascending (chunk-major x within-chunk) —
// identical FP order to the monolithic version; relu folded into W3 dot.
// Live set ~60 regs (was 150+ -> VGPR=256 spills). Per-slice top-8 with
// exact ref comparator (key desc, idx asc) -> partials.
// ---------------------------------------------------------------------------
__global__ __launch_bounds__(256, 4) void k3_refine(
    const float* __restrict__ p_th, const float* __restrict__ p_xy,
    const float* __restrict__ p_di, const float* __restrict__ p_po,
    const float* __restrict__ p_ne, const float* __restrict__ p_io,
    const float* __restrict__ W1, const float* __restrict__ b1,
    const float* __restrict__ W2, const float* __restrict__ b2,
    const float* __restrict__ W3, const float* __restrict__ b3,
    const int* __restrict__ cnt, const int* __restrict__ cand,
    int* __restrict__ t8i_p, float* __restrict__ t8k_p)
{
  __shared__ float wl[2561];
  __shared__ float ck[SLICE_CAP];
  __shared__ int   cnid[SLICE_CAP];
  const int t   = blockIdx.x >> 3;          // target
  const int b   = blockIdx.x & (K3SPLIT - 1);
  const int tid = threadIdx.x;

  for (int i = tid; i < 2561; i += 256) {
    float x;
    if (i < 384)       x = W1[i];
    else if (i < 448)  x = b1[i - 384];
    else if (i < 2496) x = W2[i - 448];
    else if (i < 2528) x = b2[i - 2496];
    else if (i < 2560) x = W3[i - 2528];
    else               x = b3[0];
    wl[i] = x;
  }
  __syncthreads();
  const float* W1L = wl;
  const float* b1L = wl + 384;
  const float* W2L = wl + 448;
  const float* b2L = wl + 2496;
  const float* W3L = wl + 2528;
  const float  b3s = wl[2560];

  int m = cnt[t];
  if (m > CAP) m = CAP;
  const int mloc = (b < m) ? (m - b + K3SPLIT - 1) / K3SPLIT : 0;

  for (int k = tid; k < mloc; k += 256) {
    const int i = b + k * K3SPLIT;          // global candidate index, < m
    const int n = cand[(size_t)t * CAP + i];
    const size_t off = (size_t)n * 128 + t;
    float f[6];
    f[0] = 1.0f - fminf(p_th[off], 180.0f) / 180.0f;
    f[1] = 1.0f - fminf(p_xy[off], 800.0f) / 800.0f;
    f[2] = 1.0f - fminf(p_di[off], 800.0f) / 800.0f;
    f[3] = p_po[off]; f[4] = p_ne[off]; f[5] = p_io[off];

    float h2[32];
#pragma unroll
    for (int j = 0; j < 32; ++j) h2[j] = b2L[j];

    for (int c0 = 0; c0 < 64; c0 += 16) {   // rolled: reuse h1c regs
      float h1c[16];
#pragma unroll
      for (int jj = 0; jj < 16; ++jj) {
        float s = b1L[c0 + jj];
#pragma unroll
        for (int k2 = 0; k2 < 6; ++k2)
          s = fmaf(f[k2], W1L[k2 * 64 + c0 + jj], s);
        h1c[jj] = fmaxf(s, 0.0f);
      }
#pragma unroll
      for (int j = 0; j < 32; ++j) {
        float s = h2[j];
#pragma unroll
        for (int jj = 0; jj < 16; ++jj)
          s = fmaf(h1c[jj], W2L[(c0 + jj) * 32 + j], s);
        h2[j] = s;
      }
    }

    float lo = b3s;
#pragma unroll
    for (int k2 = 0; k2 < 32; ++k2)
      lo = fmaf(fmaxf(h2[k2], 0.0f), W3L[k2], lo);
    const float sg = 1.0f / (1.0f + expf(-lo));
    ck[k]   = (sg < 0.5f) ? 0.0f : sg;
    cnid[k] = n;
  }
  __syncthreads();

  if (tid == 0) {
    float bv[8]; int bi[8];
#pragma unroll
    for (int q = 0; q < 8; ++q) { bv[q] = -1.0f; bi[q] = 0x7fffffff; }
    for (int i = 0; i < mloc; ++i) {
      const float x = ck[i];
      const int   n = cnid[i];
      if (x > bv[7] || (x == bv[7] && n < bi[7])) {
        int k = 7;
        while (k > 0 && (x > bv[k - 1] || (x == bv[k - 1] && n < bi[k - 1]))) {
          bv[k] = bv[k - 1]; bi[k] = bi[k - 1]; --k;
        }
        bv[k] = x; bi[k] = n;
      }
    }
    const int o = (t * K3SPLIT + b) * 8;
#pragma unroll
    for (int q = 0; q < 8; ++q) {
      t8i_p[o + q] = bi[q];
      t8k_p[o + q] = bv[q];
    }
  }
}

// ---------------------------------------------------------------------------
// K4: stable descending argsort of targets[:,1]; merge the 8x8 partials per
// target (same comparator -> identical selection); assemble outputs.
// d_out (int32): rows[1024] | cols[1024] | valid[1024]
// ---------------------------------------------------------------------------
__global__ void k4_final(const float* __restrict__ targets,
                         const int* __restrict__ t8i_p,
                         const float* __restrict__ t8k_p,
                         int* __restrict__ out)
{
  __shared__ float key[128];
  __shared__ int   ord[128];
  const int i = threadIdx.x;    // 0..127
  key[i] = targets[i * 4 + 1];
  __syncthreads();
  const float ki = key[i];
  int r = 0;
  for (int j = 0; j < 128; ++j) {
    const float kj = key[j];
    r += (kj > ki) || (kj == ki && j < i);
  }
  ord[r] = i;
  __syncthreads();
  const int src = ord[i];

  float bv[8]; int bi[8];
#pragma unroll
  for (int q = 0; q < 8; ++q) { bv[q] = -1.0f; bi[q] = 0x7fffffff; }
  for (int e = 0; e < K3SPLIT * 8; ++e) {
    const float x = t8k_p[src * K3SPLIT * 8 + e];
    const int   n = t8i_p[src * K3SPLIT * 8 + e];
    if (x > bv[7] || (x == bv[7] && n < bi[7])) {
      int k = 7;
      while (k > 0 && (x > bv[k - 1] || (x == bv[k - 1] && n < bi[k - 1]))) {
        bv[k] = bv[k - 1]; bi[k] = bi[k - 1]; --k;
      }
      bv[k] = x; bi[k] = n;
    }
  }
#pragma unroll
  for (int k = 0; k < 8; ++k) {
    out[i * 8 + k]        = bi[k];
    out[1024 + i * 8 + k] = src;
    out[2048 + i * 8 + k] = (bv[k] > 0.0f) ? 1 : 0;
  }
}

// ---------------------------------------------------------------------------
extern "C" void kernel_launch(void* const* d_in, const int* in_sizes, int n_in,
                              void* d_out, int out_size, void* d_ws, size_t ws_size,
                              hipStream_t stream)
{
  const float* p_th = (const float*)d_in[0];
  const float* p_xy = (const float*)d_in[1];
  const float* p_di = (const float*)d_in[2];
  const float* p_po = (const float*)d_in[3];
  const float* p_ne = (const float*)d_in[4];
  const float* p_io = (const float*)d_in[5];
  const float* tgt  = (const float*)d_in[6];
  const float* W1   = (const float*)d_in[7];
  const float* b1   = (const float*)d_in[8];
  const float* W2   = (const float*)d_in[9];
  const float* b2   = (const float*)d_in[10];
  const float* W3   = (const float*)d_in[11];
  const float* b3   = (const float*)d_in[12];

  // workspace carve (~18.9 MB; pval and cand share a 2 MB region, disjoint
  // lifetimes: pval dead after k2b, cand born in k2c). K3/K4 partials live
  // in the lg region (lg dead after k2c reads it).
  char* base = (char*)d_ws;
  u16*   lg    = (u16*)  (base);                 // 16,777,216 B (k1..k2c)
  int*   t8i_p = (int*)  (base);                 //     32,768 B (k3..k4)
  float* t8k_p = (float*)(base + 32768);         //     32,768 B (k3..k4)
  float* pval  = (float*)(base + 16777216);      //  2,097,152 B (k2a..k2b)
  int*   cand  = (int*)  (base + 16777216);      //  2,097,152 B (k2c..k3)
  float* tau   = (float*)(base + 18874368);      //        512 B
  int*   cnt   = (int*)  (base + 18874880);      //        512 B

  hipMemsetAsync(cnt, 0, 128 * sizeof(int), stream);

  k1_mfma<<<2048, 256, 0, stream>>>(p_th, p_xy, p_di, p_po, p_ne, p_io,
                                    W1, b1, W2, b2, W3, b3, lg);
  k2a_part<<<NCHUNK, 128, 0, stream>>>(lg, pval);
  k2b_merge<<<128, 64, 0, stream>>>(pval, tau);
  k2c_cand<<<NCHUNK, 128, 0, stream>>>(lg, tau, cnt, cand);
  k3_refine<<<N_TGT * K3SPLIT, 256, 0, stream>>>(p_th, p_xy, p_di, p_po, p_ne,
                                                 p_io, W1, b1, W2, b2, W3, b3,
                                                 cnt, cand, t8i_p, t8k_p);
  k4_final<<<1, 128, 0, stream>>>(tgt, t8i_p, t8k_p, (int*)d_out);
}